// Round 4
// baseline (7346.104 us; speedup 1.0000x reference)
//
#include <hip/hip_runtime.h>
#include <hip/hip_bf16.h>
#include <stdint.h>

typedef __bf16 bf16;
typedef bf16 bf16x8 __attribute__((ext_vector_type(8)));
typedef bf16 bf16x4 __attribute__((ext_vector_type(4)));
typedef float f32x4 __attribute__((ext_vector_type(4)));

#define NB 8
#define NH 36
#define NW 100
#define YS 44
#define XSZ 108
#define PIX 28800

#define AS1 __attribute__((address_space(1)))
#define AS3 __attribute__((address_space(3)))

// async 16B global->LDS DMA. Dest = wave-uniform base + lane*16.
__device__ __forceinline__ void g2l16(const bf16* g, bf16* l) {
    __builtin_amdgcn_global_load_lds((const AS1 void*)g, (AS3 void*)l, 16, 0, 0);
}

// ---------------- workspace layout ----------------
static constexpr size_t OFF_XP = 0;
static constexpr size_t SZ_XP  = (size_t)NB*YS*XSZ*512*2;
static constexpr size_t OFF_HP = OFF_XP + SZ_XP;
static constexpr size_t SZ_HP  = (size_t)NB*YS*XSZ*128*2;
static constexpr size_t OFF_A1 = OFF_HP + SZ_HP;
static constexpr size_t SZ_A1  = (size_t)1024*4608*2;
static constexpr size_t OFF_A2 = OFF_A1 + SZ_A1;
static constexpr size_t SZ_A2  = (size_t)128*1024*2;
static constexpr size_t OFF_AW = OFF_A2 + SZ_A2;
static constexpr size_t SZ_AW  = (size_t)4*9*128*128*2;
static constexpr size_t OFF_H1 = OFF_AW + SZ_AW;
static constexpr size_t SZ_H1  = (size_t)PIX*1024*2;
static constexpr size_t OFF_S1 = OFF_H1 + SZ_H1;
static constexpr size_t OFF_T1 = OFF_S1 + 4096;
static constexpr size_t OFF_S2 = OFF_T1 + 4096;
static constexpr size_t OFF_T2 = OFF_S2 + 512;
static constexpr size_t OFF_H5 = OFF_T2 + 512;
static constexpr size_t SZ_H5  = (size_t)NB*5*3600*4;
static constexpr size_t OFF_P  = OFF_H5 + SZ_H5;
static constexpr size_t OFF_F  = OFF_P + SZ_H5;
static constexpr size_t OFF_G  = OFF_F + 144128;

// ---------------- prep kernels ----------------
__global__ __launch_bounds__(256) void zero_k(uint4* __restrict__ p, int n) {
    int i = blockIdx.x * 256 + threadIdx.x;
    if (i < n) p[i] = uint4{0u, 0u, 0u, 0u};
}

__global__ __launch_bounds__(256) void prep_x(const float* __restrict__ x, bf16* __restrict__ xp) {
    int bid = blockIdx.x;
    int xc = bid & 3;  int r = bid >> 2;
    int cc = r & 15;   r >>= 4;
    int yo = r % 36;   int b = r / 36;
    int ci0 = cc * 32, xo0 = xc * 32;
    int wdt = 100 - xo0; if (wdt > 32) wdt = 32;
    __shared__ bf16 T[32 * 33];
    int t = threadIdx.x;
    int cl = t >> 5, xl = t & 31;
    if (xl < wdt) {
#pragma unroll
        for (int i = 0; i < 4; i++) {
            int ci = ci0 + cl + 8 * i;
            T[(cl + 8 * i) * 33 + xl] = (bf16)x[((size_t)(b * 512 + ci) * 36 + yo) * 100 + xo0 + xl];
        }
    }
    __syncthreads();
    if (t < 128) {
        int xo2 = t >> 2, oct = t & 3;
        if (xo2 < wdt) {
            bf16x8 vv;
#pragma unroll
            for (int j = 0; j < 8; j++) vv[j] = T[(oct * 8 + j) * 33 + xo2];
            *(bf16x8*)(xp + ((size_t)((b * YS + yo + 4) * XSZ) + xo0 + xo2 + 4) * 512 + ci0 + oct * 8) = vv;
        }
    }
}

__global__ __launch_bounds__(256) void prep_w1a(const float* __restrict__ w, bf16* __restrict__ A) {
    int co = blockIdx.x;
    __shared__ bf16 Wl[4608];
    const float* src = w + (size_t)co * 4608;
    for (int v = threadIdx.x; v < 4608; v += 256) Wl[v] = (bf16)src[v];
    __syncthreads();
    bf16* dst = A + (size_t)co * 4608;
    for (int v = threadIdx.x; v < 4608; v += 256) {
        int rr = v >> 9, ci = v & 511;
        dst[v] = Wl[ci * 9 + rr];
    }
}

__global__ __launch_bounds__(256) void prep_w1b(const float* __restrict__ w, bf16* __restrict__ A) {
    int i = blockIdx.x * 256 + threadIdx.x;
    if (i < 131072) A[i] = (bf16)w[i];
}

__global__ __launch_bounds__(256) void prep_msg(const float* __restrict__ w0, const float* __restrict__ w1,
                                                const float* __restrict__ w2m, const float* __restrict__ w3,
                                                bf16* __restrict__ Aw) {
    int idx = blockIdx.x * 256 + threadIdx.x;
    if (idx >= 4 * 147456) return;
    int w = idx / 147456, r = idx % 147456;
    int t9 = r / 16384, r2 = r % 16384;
    int co = r2 >> 7, ci = r2 & 127;
    const float* s = (w == 0) ? w0 : (w == 1) ? w1 : (w == 2) ? w2m : w3;
    Aw[idx] = (bf16)s[(co * 128 + ci) * 9 + t9];
}

__global__ __launch_bounds__(256) void prep_bn(const float* g1, const float* b1, const float* m1, const float* v1,
                                               const float* g2, const float* b2i, const float* m2, const float* v2,
                                               float* s1, float* t1, float* s2, float* t2) {
    int i = blockIdx.x * 256 + threadIdx.x;
    if (i < 1024) {
        float s = g1[i] / sqrtf(v1[i] + 1e-5f);
        s1[i] = s; t1[i] = b1[i] - m1[i] * s;
    } else if (i < 1152) {
        int c = i - 1024;
        float s = g2[c] / sqrtf(v2[c] + 1e-5f);
        s2[c] = s; t2[c] = b2i[c] - m2[c] * s;
    }
}

// ---------------- conv1: implicit-im2col GEMM, global_load_lds + swizzled LDS ----------------
__device__ __forceinline__ void c1_koff(int ch, int& k0, int& xoff) {
    int ky = ch / 48, rem = ch - ky * 48;
    int kx = rem >> 4, c0 = (rem & 15) << 5;
    k0 = (ky * 3 + kx) * 512 + c0;
    xoff = (ky * XSZ + kx) * 2048 + c0;
}

__device__ __forceinline__ bf16x8 lds_frag(const bf16* S, int row, int q) {
    return *(const bf16x8*)(S + row * 32 + (((q ^ (row >> 1)) & 3) * 8));
}

__global__ __launch_bounds__(256) void conv1_gemm(const bf16* __restrict__ A, const bf16* __restrict__ xp,
                                                  const float* __restrict__ s1, const float* __restrict__ t1,
                                                  bf16* __restrict__ h1) {
    __shared__ __align__(16) bf16 SH[17408];
    bf16* As = SH;
    bf16* Bs = SH + 4096;
    const int t = threadIdx.x;
    const int pt = blockIdx.x, ct = blockIdx.y;
    const int co0 = ct * 128, p0 = pt * 128;
    const int wid = t >> 6, lane = t & 63;

    int aOff[2], bOff[2], ldsOff[2];
#pragma unroll
    for (int j = 0; j < 2; j++) {
        int p = wid * 128 + j * 64 + lane;
        int row = p >> 2;
        int oc = (p & 3) ^ ((p >> 3) & 3);
        aOff[j] = (co0 + row) * 4608 + oc * 8;
        int px = p0 + row;
        int b = px / 3600, rr = px % 3600;
        int y = rr / 100, xx = rr % 100;
        bOff[j] = ((b * YS + y) * XSZ + xx) * 512 + oc * 8;
        ldsOff[j] = (wid * 128 + j * 64) * 8;
    }

    const int mbase = (wid & 1) * 64, nbase = (wid >> 1) * 64;
    const int l15 = lane & 15, q = lane >> 4;

    f32x4 acc[4][4];
#pragma unroll
    for (int i = 0; i < 4; i++)
#pragma unroll
        for (int j = 0; j < 4; j++) acc[i][j] = f32x4{0.f, 0.f, 0.f, 0.f};

    for (int ch = 0; ch < 144; ch++) {
        int k0, xoff;
        c1_koff(ch, k0, xoff);
        __syncthreads();
#pragma unroll
        for (int j = 0; j < 2; j++) {
            g2l16(A + aOff[j] + k0, As + ldsOff[j]);
            g2l16(xp + bOff[j] + xoff, Bs + ldsOff[j]);
        }
        __syncthreads();
        bf16x8 af[4], bfv[4];
#pragma unroll
        for (int mt = 0; mt < 4; mt++) af[mt] = lds_frag(As, mbase + mt * 16 + l15, q);
#pragma unroll
        for (int nt = 0; nt < 4; nt++) bfv[nt] = lds_frag(Bs, nbase + nt * 16 + l15, q);
#pragma unroll
        for (int mt = 0; mt < 4; mt++)
#pragma unroll
            for (int nt = 0; nt < 4; nt++)
                acc[mt][nt] = __builtin_amdgcn_mfma_f32_16x16x32_bf16(af[mt], bfv[nt], acc[mt][nt], 0, 0, 0);
    }

    __syncthreads();
#pragma unroll
    for (int mt = 0; mt < 4; mt++) {
        int co = co0 + mbase + mt * 16 + q * 4;
        f32x4 sc = *(const f32x4*)(s1 + co);
        f32x4 tc = *(const f32x4*)(t1 + co);
#pragma unroll
        for (int nt = 0; nt < 4; nt++) {
            int pxl = nbase + nt * 16 + l15;
            bf16x4 o;
#pragma unroll
            for (int r = 0; r < 4; r++) {
                float v = acc[mt][nt][r] * sc[r] + tc[r];
                o[r] = (bf16)(v > 0.f ? v : 0.f);
            }
            *(bf16x4*)(SH + pxl * 136 + mbase + mt * 16 + q * 4) = o;
        }
    }
    __syncthreads();
#pragma unroll
    for (int i = 0; i < 8; i++) {
        int v = t + 256 * i;
        int pxl = v >> 4, c16 = v & 15;
        *(uint4*)(h1 + (size_t)(p0 + pxl) * 1024 + co0 + c16 * 8) = *(const uint4*)(SH + pxl * 136 + c16 * 8);
    }
}

// ---------------- conv2: 1x1 1024->128 ----------------
__global__ __launch_bounds__(256) void conv2_gemm(const bf16* __restrict__ A2, const bf16* __restrict__ h1,
                                                  const float* __restrict__ s2, const float* __restrict__ t2,
                                                  bf16* __restrict__ hp) {
    __shared__ __align__(16) bf16 SH[17408];
    bf16* As = SH;
    bf16* Bs = SH + 4096;
    const int t = threadIdx.x;
    const int p0 = blockIdx.x * 128;
    const int wid = t >> 6, lane = t & 63;

    int aOff[2], bOff[2], ldsOff[2];
#pragma unroll
    for (int j = 0; j < 2; j++) {
        int p = wid * 128 + j * 64 + lane;
        int row = p >> 2;
        int oc = (p & 3) ^ ((p >> 3) & 3);
        aOff[j] = row * 1024 + oc * 8;
        bOff[j] = (p0 + row) * 1024 + oc * 8;
        ldsOff[j] = (wid * 128 + j * 64) * 8;
    }
    const int mbase = (wid & 1) * 64, nbase = (wid >> 1) * 64;
    const int l15 = lane & 15, q = lane >> 4;

    f32x4 acc[4][4];
#pragma unroll
    for (int i = 0; i < 4; i++)
#pragma unroll
        for (int j = 0; j < 4; j++) acc[i][j] = f32x4{0.f, 0.f, 0.f, 0.f};

    for (int ch = 0; ch < 32; ch++) {
        int k0 = ch * 32;
        __syncthreads();
#pragma unroll
        for (int j = 0; j < 2; j++) {
            g2l16(A2 + aOff[j] + k0, As + ldsOff[j]);
            g2l16(h1 + bOff[j] + k0, Bs + ldsOff[j]);
        }
        __syncthreads();
        bf16x8 af[4], bfv[4];
#pragma unroll
        for (int mt = 0; mt < 4; mt++) af[mt] = lds_frag(As, mbase + mt * 16 + l15, q);
#pragma unroll
        for (int nt = 0; nt < 4; nt++) bfv[nt] = lds_frag(Bs, nbase + nt * 16 + l15, q);
#pragma unroll
        for (int mt = 0; mt < 4; mt++)
#pragma unroll
            for (int nt = 0; nt < 4; nt++)
                acc[mt][nt] = __builtin_amdgcn_mfma_f32_16x16x32_bf16(af[mt], bfv[nt], acc[mt][nt], 0, 0, 0);
    }

    __syncthreads();
#pragma unroll
    for (int mt = 0; mt < 4; mt++) {
        int co = mbase + mt * 16 + q * 4;
        f32x4 sc = *(const f32x4*)(s2 + co);
        f32x4 tc = *(const f32x4*)(t2 + co);
#pragma unroll
        for (int nt = 0; nt < 4; nt++) {
            int pxl = nbase + nt * 16 + l15;
            bf16x4 o;
#pragma unroll
            for (int r = 0; r < 4; r++) {
                float v = acc[mt][nt][r] * sc[r] + tc[r];
                o[r] = (bf16)(v > 0.f ? v : 0.f);
            }
            *(bf16x4*)(SH + pxl * 136 + co) = o;
        }
    }
    __syncthreads();
#pragma unroll
    for (int i = 0; i < 8; i++) {
        int v = t + 256 * i;
        int pxl = v >> 4, c16 = v & 15;
        int p = p0 + pxl;
        int b = p / 3600, rr = p % 3600;
        int y = rr / 100, xx = rr % 100;
        *(uint4*)(hp + (size_t)((b * YS + y + 4) * XSZ + xx + 4) * 128 + c16 * 8) = *(const uint4*)(SH + pxl * 136 + c16 * 8);
    }
}

// ---------------- message passes ----------------
// wave = n-tile group (all 128 co per wave). A streamed from L2 via depth-3
// register pipeline; B read once per tile from LDS. __launch_bounds__(256,1)
// grants the 512-VGPR budget (1 wave/SIMD) so nothing spills.
__device__ __forceinline__ bf16x8 awfrag(const bf16* __restrict__ Aw, int ch, int mt, int l15, int q) {
    int t9 = ch >> 2, c0 = (ch & 3) << 5;
    return *(const bf16x8*)(Aw + (size_t)((t9 * 128 + mt * 16 + l15) << 7) + c0 + q * 8);
}

template <int AX, int RV>
__global__ __launch_bounds__(256, 1) void msg_pass(const bf16* __restrict__ Aw, bf16* __restrict__ hp) {
    constexpr int LINE2 = (AX == 2) ? 120 : 56;   // Rb rows (incl. read-overshoot)
    constexpr int LINE  = (AX == 2) ? XSZ : YS;   // staged rows
    constexpr int STEPS = (AX == 2) ? NH : NW;
    constexpr int NLIM  = (AX == 2) ? NW : NH;
    constexpr int NTW   = (AX == 2) ? 2 : 1;      // n-tiles per wave
    __shared__ __align__(16) bf16 Rb[LINE2 * 136];
    const int b = blockIdx.x;
    const int t = threadIdx.x;
    const int wid = t >> 6, lane = t & 63, l15 = lane & 15, q = lane >> 4;
    // tile sets: AX2 {0,1}{2,3}{4,5}{5,6} ; AX3 {0}{1}{2}{2}. wid3's first
    // tile duplicates wid2's last -> compute is benign-dup, stores skipped.
    const int ntBase = (AX == 2) ? ((wid < 3) ? wid * 2 : 5) : ((wid < 3) ? wid : 2);
    bf16* hpb = hp + (size_t)b * YS * XSZ * 128;

    // stage first (unchanged) line into LDS, incl. zero borders
    if (AX == 2) {
        int ys0 = RV ? 39 : 4;
        for (int v = t; v < LINE * 16; v += 256) {
            int xs = v >> 4, oct = v & 15;
            *(uint4*)(Rb + xs * 136 + oct * 8) = *(const uint4*)(hpb + ((size_t)ys0 * XSZ + xs) * 128 + oct * 8);
        }
    } else {
        int xs0 = RV ? 103 : 4;
        for (int v = t; v < LINE * 16; v += 256) {
            int ys = v >> 4, oct = v & 15;
            *(uint4*)(Rb + ys * 136 + oct * 8) = *(const uint4*)(hpb + ((size_t)ys * XSZ + xs0) * 128 + oct * 8);
        }
    }

    for (int s = 1; s < STEPS; s++) {
        int pos = RV ? (STEPS - 1 - s) : s;

        // A-pipeline preload (global only — overlaps the barrier)
        bf16x8 apipe[3][8];
#pragma unroll
        for (int p = 0; p < 3; p++)
#pragma unroll
            for (int mt = 0; mt < 8; mt++) apipe[p][mt] = awfrag(Aw, p, mt, l15, q);

        __syncthreads();                           // prev line in Rb ready

        f32x4 acc[8][NTW];
#pragma unroll
        for (int mt = 0; mt < 8; mt++)
#pragma unroll
            for (int ntl = 0; ntl < NTW; ntl++) acc[mt][ntl] = f32x4{0.f, 0.f, 0.f, 0.f};

#pragma unroll
        for (int ch = 0; ch < 36; ch++) {
            int t9 = ch >> 2, c0 = (ch & 3) << 5;
            bf16x8 bfv[NTW];
#pragma unroll
            for (int ntl = 0; ntl < NTW; ntl++) {
                int n = (ntBase + ntl) * 16 + l15;
                bfv[ntl] = *(const bf16x8*)(Rb + (n + t9) * 136 + c0 + q * 8);
            }
#pragma unroll
            for (int mt = 0; mt < 8; mt++)
#pragma unroll
                for (int ntl = 0; ntl < NTW; ntl++)
                    acc[mt][ntl] = __builtin_amdgcn_mfma_f32_16x16x32_bf16(apipe[ch % 3][mt], bfv[ntl], acc[mt][ntl], 0, 0, 0);
            if (ch + 3 < 36) {
#pragma unroll
                for (int mt = 0; mt < 8; mt++) apipe[ch % 3][mt] = awfrag(Aw, ch + 3, mt, l15, q);
            }
        }
        __syncthreads();                           // Rb reads done before overwrite

        // phase A: batch-load RMW operands
        bf16x4 curv[8][NTW];
#pragma unroll
        for (int mt = 0; mt < 8; mt++) {
            int co = mt * 16 + q * 4;
#pragma unroll
            for (int ntl = 0; ntl < NTW; ntl++) {
                if (wid == 3 && ntl == 0) continue;   // duplicated tile
                int n = (ntBase + ntl) * 16 + l15;
                if (n < NLIM) {
                    int g = (AX == 2) ? ((pos + 4) * XSZ + (n + 4)) * 128 + co
                                      : ((n + 4) * XSZ + (pos + 4)) * 128 + co;
                    curv[mt][ntl] = *(const bf16x4*)(hpb + g);
                }
            }
        }
        // phase B: add relu(acc), store to global + Rb
#pragma unroll
        for (int mt = 0; mt < 8; mt++) {
            int co = mt * 16 + q * 4;
#pragma unroll
            for (int ntl = 0; ntl < NTW; ntl++) {
                if (wid == 3 && ntl == 0) continue;
                int n = (ntBase + ntl) * 16 + l15;
                if (n < NLIM) {
                    int g = (AX == 2) ? ((pos + 4) * XSZ + (n + 4)) * 128 + co
                                      : ((n + 4) * XSZ + (pos + 4)) * 128 + co;
                    bf16x4 o;
#pragma unroll
                    for (int r = 0; r < 4; r++) {
                        float v = acc[mt][ntl][r];
                        v = v > 0.f ? v : 0.f;
                        o[r] = (bf16)((float)curv[mt][ntl][r] + v);
                    }
                    *(bf16x4*)(hpb + g) = o;
                    *(bf16x4*)(Rb + (n + 4) * 136 + co) = o;
                }
            }
        }
    }
}

// ---------------- conv3 (1x1 128->5) + bias + softmax ----------------
__global__ __launch_bounds__(256) void conv3_softmax(const bf16* __restrict__ hp, const float* __restrict__ w2,
                                                     const float* __restrict__ b2, float* __restrict__ h5,
                                                     float* __restrict__ Pp) {
    int idx = blockIdx.x * 256 + threadIdx.x;
    if (idx >= PIX) return;
    int b = idx / 3600, rr = idx % 3600;
    int y = rr / 100, xx = rr % 100;
    const bf16* src = hp + ((size_t)(b * YS + y + 4) * XSZ + xx + 4) * 128;
    float a[5] = {b2[0], b2[1], b2[2], b2[3], b2[4]};
    for (int c8 = 0; c8 < 128; c8 += 8) {
        bf16x8 hv = *(const bf16x8*)(src + c8);
#pragma unroll
        for (int j = 0; j < 8; j++) {
            float hf = (float)hv[j];
            int c = c8 + j;
#pragma unroll
            for (int o = 0; o < 5; o++) a[o] += hf * w2[o * 128 + c];
        }
    }
    float mx = a[0];
#pragma unroll
    for (int o = 1; o < 5; o++) mx = a[o] > mx ? a[o] : mx;
    float e[5], sum = 0.f;
#pragma unroll
    for (int o = 0; o < 5; o++) { e[o] = expf(a[o] - mx); sum += e[o]; }
    float inv = 1.f / sum;
#pragma unroll
    for (int o = 0; o < 5; o++) {
        h5[(size_t)(b * 5 + o) * 3600 + rr] = a[o];
        Pp[(size_t)(b * 5 + o) * 3600 + rr] = e[o] * inv;
    }
}

__global__ __launch_bounds__(256) void pool_k(const float* __restrict__ Pp, float* __restrict__ F) {
    int idx = blockIdx.x * 256 + threadIdx.x;
    if (idx >= 36000) return;
    int xxp = idx % 50, r = idx / 50;
    int yyp = r % 18, bj = r / 18;
    int b = bj / 5, j = bj % 5;
    const float* Pb = Pp + (size_t)bj * 3600;
    float v = 0.25f * (Pb[(2 * yyp) * 100 + 2 * xxp] + Pb[(2 * yyp) * 100 + 2 * xxp + 1] +
                       Pb[(2 * yyp + 1) * 100 + 2 * xxp] + Pb[(2 * yyp + 1) * 100 + 2 * xxp + 1]);
    F[(size_t)b * 4500 + j * 900 + yyp * 50 + xxp] = v;
}

__global__ __launch_bounds__(64) void fc1_k(const float* __restrict__ F, const float* __restrict__ w,
                                            const float* __restrict__ bias, float* __restrict__ G) {
    int co = blockIdx.x;
    int lane = threadIdx.x;
    const float* wr = w + (size_t)co * 4500;
    float a[8] = {0.f, 0.f, 0.f, 0.f, 0.f, 0.f, 0.f, 0.f};
    for (int k = lane; k < 4500; k += 64) {
        float wv = wr[k];
#pragma unroll
        for (int b = 0; b < 8; b++) a[b] += wv * F[b * 4500 + k];
    }
#pragma unroll
    for (int b = 0; b < 8; b++) {
        float r = a[b];
        for (int off = 32; off; off >>= 1) r += __shfl_down(r, off);
        if (lane == 0) {
            float v = r + bias[co];
            G[b * 128 + co] = v > 0.f ? v : 0.f;
        }
    }
}

__global__ __launch_bounds__(64) void fc2_k(const float* __restrict__ G, const float* __restrict__ w,
                                            const float* __restrict__ bias, float* __restrict__ out) {
    int t = threadIdx.x;
    if (t >= 32) return;
    int b = t >> 2, j = t & 3;
    float a = bias[j];
    for (int c = 0; c < 128; c++) a += G[b * 128 + c] * w[j * 128 + c];
    out[9216000 + b * 4 + j] = 1.f / (1.f + expf(-a));
}

__global__ __launch_bounds__(256) void upsample_k(const float* __restrict__ h5, float* __restrict__ out) {
    int idx = blockIdx.x * 256 + threadIdx.x;
    if (idx >= 2304000) return;
    int xq = idx % 200, r = idx / 200;
    int yo = r % 288, bj = r / 288;
    const float* src = h5 + (size_t)bj * 3600;
    float py = yo * (35.0f / 287.0f);
    int i0 = (int)py; if (i0 > 34) i0 = 34;
    float fh = py - (float)i0;
    const float* r0 = src + i0 * 100;
    const float* r1 = r0 + 100;
    float4 o;
    float res[4];
#pragma unroll
    for (int e = 0; e < 4; e++) {
        int xo = xq * 4 + e;
        float px = xo * (99.0f / 799.0f);
        int j0 = (int)px; if (j0 > 98) j0 = 98;
        float fw = px - (float)j0;
        float aa = r0[j0] * (1.f - fh) + r1[j0] * fh;
        float bb = r0[j0 + 1] * (1.f - fh) + r1[j0 + 1] * fh;
        res[e] = aa * (1.f - fw) + bb * fw;
    }
    o.x = res[0]; o.y = res[1]; o.z = res[2]; o.w = res[3];
    *(float4*)(out + (size_t)idx * 4) = o;
}

// ---------------- launcher ----------------
extern "C" void kernel_launch(void* const* d_in, const int* in_sizes, int n_in,
                              void* d_out, int out_size, void* d_ws, size_t ws_size,
                              hipStream_t stream) {
    (void)in_sizes; (void)n_in; (void)out_size; (void)ws_size;
    const float* x    = (const float*)d_in[0];
    const float* w1a  = (const float*)d_in[1];
    const float* bn1g = (const float*)d_in[2];
    const float* bn1b = (const float*)d_in[3];
    const float* bn1m = (const float*)d_in[4];
    const float* bn1v = (const float*)d_in[5];
    const float* w1b  = (const float*)d_in[6];
    const float* bn2g = (const float*)d_in[7];
    const float* bn2b = (const float*)d_in[8];
    const float* bn2m = (const float*)d_in[9];
    const float* bn2v = (const float*)d_in[10];
    const float* wud  = (const float*)d_in[11];
    const float* wdu  = (const float*)d_in[12];
    const float* wlr  = (const float*)d_in[13];
    const float* wrl  = (const float*)d_in[14];
    const float* w2   = (const float*)d_in[15];
    const float* b2   = (const float*)d_in[16];
    const float* fc1w = (const float*)d_in[17];
    const float* fc1b = (const float*)d_in[18];
    const float* fc2w = (const float*)d_in[19];
    const float* fc2b = (const float*)d_in[20];
    float* out = (float*)d_out;
    char* ws = (char*)d_ws;
    bf16* xp = (bf16*)(ws + OFF_XP);
    bf16* hp = (bf16*)(ws + OFF_HP);
    bf16* A1 = (bf16*)(ws + OFF_A1);
    bf16* A2 = (bf16*)(ws + OFF_A2);
    bf16* Aw = (bf16*)(ws + OFF_AW);
    bf16* h1 = (bf16*)(ws + OFF_H1);
    float* s1 = (float*)(ws + OFF_S1);
    float* t1 = (float*)(ws + OFF_T1);
    float* s2 = (float*)(ws + OFF_S2);
    float* t2 = (float*)(ws + OFF_T2);
    float* h5 = (float*)(ws + OFF_H5);
    float* Pp = (float*)(ws + OFF_P);
    float* Ff = (float*)(ws + OFF_F);
    float* Gg = (float*)(ws + OFF_G);

    int nzero = (int)((SZ_XP + SZ_HP) / 16);
    zero_k<<<(nzero + 255) / 256, 256, 0, stream>>>((uint4*)ws, nzero);
    prep_x<<<18432, 256, 0, stream>>>(x, xp);
    prep_w1a<<<1024, 256, 0, stream>>>(w1a, A1);
    prep_w1b<<<512, 256, 0, stream>>>(w1b, A2);
    prep_msg<<<2304, 256, 0, stream>>>(wud, wdu, wlr, wrl, Aw);
    prep_bn<<<5, 256, 0, stream>>>(bn1g, bn1b, bn1m, bn1v, bn2g, bn2b, bn2m, bn2v, s1, t1, s2, t2);

    conv1_gemm<<<dim3(225, 8), 256, 0, stream>>>(A1, xp, s1, t1, h1);
    conv2_gemm<<<225, 256, 0, stream>>>(A2, h1, s2, t2, hp);

    msg_pass<2, 0><<<NB, 256, 0, stream>>>(Aw + 0 * 147456, hp);
    msg_pass<2, 1><<<NB, 256, 0, stream>>>(Aw + 1 * 147456, hp);
    msg_pass<3, 0><<<NB, 256, 0, stream>>>(Aw + 2 * 147456, hp);
    msg_pass<3, 1><<<NB, 256, 0, stream>>>(Aw + 3 * 147456, hp);

    conv3_softmax<<<113, 256, 0, stream>>>(hp, w2, b2, h5, Pp);
    pool_k<<<141, 256, 0, stream>>>(Pp, Ff);
    fc1_k<<<128, 64, 0, stream>>>(Ff, fc1w, fc1b, Gg);
    fc2_k<<<1, 64, 0, stream>>>(Gg, fc2w, fc2b, out);
    upsample_k<<<9000, 256, 0, stream>>>(h5, out);
}

// Round 5
// 2406.364 us; speedup vs baseline: 3.0528x; 3.0528x over previous
//
#include <hip/hip_runtime.h>
#include <hip/hip_bf16.h>
#include <stdint.h>

typedef __bf16 bf16;
typedef bf16 bf16x8 __attribute__((ext_vector_type(8)));
typedef bf16 bf16x4 __attribute__((ext_vector_type(4)));
typedef float f32x4 __attribute__((ext_vector_type(4)));

#define NB 8
#define NH 36
#define NW 100
#define YS 44
#define XSZ 108
#define PIX 28800

#define AS1 __attribute__((address_space(1)))
#define AS3 __attribute__((address_space(3)))

// async 16B global->LDS DMA. Dest = wave-uniform base + lane*16.
__device__ __forceinline__ void g2l16(const bf16* g, bf16* l) {
    __builtin_amdgcn_global_load_lds((const AS1 void*)g, (AS3 void*)l, 16, 0, 0);
}

// ---------------- workspace layout ----------------
static constexpr size_t OFF_XP = 0;
static constexpr size_t SZ_XP  = (size_t)NB*YS*XSZ*512*2;
static constexpr size_t OFF_HP = OFF_XP + SZ_XP;
static constexpr size_t SZ_HP  = (size_t)NB*YS*XSZ*128*2;
static constexpr size_t OFF_A1 = OFF_HP + SZ_HP;
static constexpr size_t SZ_A1  = (size_t)1024*4608*2;
static constexpr size_t OFF_A2 = OFF_A1 + SZ_A1;
static constexpr size_t SZ_A2  = (size_t)128*1024*2;
static constexpr size_t OFF_AW = OFF_A2 + SZ_A2;
static constexpr size_t SZ_AW  = (size_t)4*9*128*128*2;
static constexpr size_t OFF_H1 = OFF_AW + SZ_AW;
static constexpr size_t SZ_H1  = (size_t)PIX*1024*2;
static constexpr size_t OFF_S1 = OFF_H1 + SZ_H1;
static constexpr size_t OFF_T1 = OFF_S1 + 4096;
static constexpr size_t OFF_S2 = OFF_T1 + 4096;
static constexpr size_t OFF_T2 = OFF_S2 + 512;
static constexpr size_t OFF_H5 = OFF_T2 + 512;
static constexpr size_t SZ_H5  = (size_t)NB*5*3600*4;
static constexpr size_t OFF_P  = OFF_H5 + SZ_H5;
static constexpr size_t OFF_F  = OFF_P + SZ_H5;
static constexpr size_t OFF_G  = OFF_F + 144128;

// ---------------- prep kernels ----------------
__global__ __launch_bounds__(256) void zero_k(uint4* __restrict__ p, int n) {
    int i = blockIdx.x * 256 + threadIdx.x;
    if (i < n) p[i] = uint4{0u, 0u, 0u, 0u};
}

__global__ __launch_bounds__(256) void prep_x(const float* __restrict__ x, bf16* __restrict__ xp) {
    int bid = blockIdx.x;
    int xc = bid & 3;  int r = bid >> 2;
    int cc = r & 15;   r >>= 4;
    int yo = r % 36;   int b = r / 36;
    int ci0 = cc * 32, xo0 = xc * 32;
    int wdt = 100 - xo0; if (wdt > 32) wdt = 32;
    __shared__ bf16 T[32 * 33];
    int t = threadIdx.x;
    int cl = t >> 5, xl = t & 31;
    if (xl < wdt) {
#pragma unroll
        for (int i = 0; i < 4; i++) {
            int ci = ci0 + cl + 8 * i;
            T[(cl + 8 * i) * 33 + xl] = (bf16)x[((size_t)(b * 512 + ci) * 36 + yo) * 100 + xo0 + xl];
        }
    }
    __syncthreads();
    if (t < 128) {
        int xo2 = t >> 2, oct = t & 3;
        if (xo2 < wdt) {
            bf16x8 vv;
#pragma unroll
            for (int j = 0; j < 8; j++) vv[j] = T[(oct * 8 + j) * 33 + xo2];
            *(bf16x8*)(xp + ((size_t)((b * YS + yo + 4) * XSZ) + xo0 + xo2 + 4) * 512 + ci0 + oct * 8) = vv;
        }
    }
}

__global__ __launch_bounds__(256) void prep_w1a(const float* __restrict__ w, bf16* __restrict__ A) {
    int co = blockIdx.x;
    __shared__ bf16 Wl[4608];
    const float* src = w + (size_t)co * 4608;
    for (int v = threadIdx.x; v < 4608; v += 256) Wl[v] = (bf16)src[v];
    __syncthreads();
    bf16* dst = A + (size_t)co * 4608;
    for (int v = threadIdx.x; v < 4608; v += 256) {
        int rr = v >> 9, ci = v & 511;
        dst[v] = Wl[ci * 9 + rr];
    }
}

__global__ __launch_bounds__(256) void prep_w1b(const float* __restrict__ w, bf16* __restrict__ A) {
    int i = blockIdx.x * 256 + threadIdx.x;
    if (i < 131072) A[i] = (bf16)w[i];
}

__global__ __launch_bounds__(256) void prep_msg(const float* __restrict__ w0, const float* __restrict__ w1,
                                                const float* __restrict__ w2m, const float* __restrict__ w3,
                                                bf16* __restrict__ Aw) {
    int idx = blockIdx.x * 256 + threadIdx.x;
    if (idx >= 4 * 147456) return;
    int w = idx / 147456, r = idx % 147456;
    int t9 = r / 16384, r2 = r % 16384;
    int co = r2 >> 7, ci = r2 & 127;
    const float* s = (w == 0) ? w0 : (w == 1) ? w1 : (w == 2) ? w2m : w3;
    Aw[idx] = (bf16)s[(co * 128 + ci) * 9 + t9];
}

__global__ __launch_bounds__(256) void prep_bn(const float* g1, const float* b1, const float* m1, const float* v1,
                                               const float* g2, const float* b2i, const float* m2, const float* v2,
                                               float* s1, float* t1, float* s2, float* t2) {
    int i = blockIdx.x * 256 + threadIdx.x;
    if (i < 1024) {
        float s = g1[i] / sqrtf(v1[i] + 1e-5f);
        s1[i] = s; t1[i] = b1[i] - m1[i] * s;
    } else if (i < 1152) {
        int c = i - 1024;
        float s = g2[c] / sqrtf(v2[c] + 1e-5f);
        s2[c] = s; t2[c] = b2i[c] - m2[c] * s;
    }
}

// ---------------- conv1: implicit-im2col GEMM, global_load_lds + swizzled LDS ----------------
__device__ __forceinline__ void c1_koff(int ch, int& k0, int& xoff) {
    int ky = ch / 48, rem = ch - ky * 48;
    int kx = rem >> 4, c0 = (rem & 15) << 5;
    k0 = (ky * 3 + kx) * 512 + c0;
    xoff = (ky * XSZ + kx) * 2048 + c0;
}

__device__ __forceinline__ bf16x8 lds_frag(const bf16* S, int row, int q) {
    return *(const bf16x8*)(S + row * 32 + (((q ^ (row >> 1)) & 3) * 8));
}

__global__ __launch_bounds__(256) void conv1_gemm(const bf16* __restrict__ A, const bf16* __restrict__ xp,
                                                  const float* __restrict__ s1, const float* __restrict__ t1,
                                                  bf16* __restrict__ h1) {
    __shared__ __align__(16) bf16 SH[17408];
    bf16* As = SH;
    bf16* Bs = SH + 4096;
    const int t = threadIdx.x;
    const int pt = blockIdx.x, ct = blockIdx.y;
    const int co0 = ct * 128, p0 = pt * 128;
    const int wid = t >> 6, lane = t & 63;

    int aOff[2], bOff[2], ldsOff[2];
#pragma unroll
    for (int j = 0; j < 2; j++) {
        int p = wid * 128 + j * 64 + lane;
        int row = p >> 2;
        int oc = (p & 3) ^ ((p >> 3) & 3);
        aOff[j] = (co0 + row) * 4608 + oc * 8;
        int px = p0 + row;
        int b = px / 3600, rr = px % 3600;
        int y = rr / 100, xx = rr % 100;
        bOff[j] = ((b * YS + y) * XSZ + xx) * 512 + oc * 8;
        ldsOff[j] = (wid * 128 + j * 64) * 8;
    }

    const int mbase = (wid & 1) * 64, nbase = (wid >> 1) * 64;
    const int l15 = lane & 15, q = lane >> 4;

    f32x4 acc[4][4];
#pragma unroll
    for (int i = 0; i < 4; i++)
#pragma unroll
        for (int j = 0; j < 4; j++) acc[i][j] = f32x4{0.f, 0.f, 0.f, 0.f};

    for (int ch = 0; ch < 144; ch++) {
        int k0, xoff;
        c1_koff(ch, k0, xoff);
        __syncthreads();
#pragma unroll
        for (int j = 0; j < 2; j++) {
            g2l16(A + aOff[j] + k0, As + ldsOff[j]);
            g2l16(xp + bOff[j] + xoff, Bs + ldsOff[j]);
        }
        __syncthreads();
        bf16x8 af[4], bfv[4];
#pragma unroll
        for (int mt = 0; mt < 4; mt++) af[mt] = lds_frag(As, mbase + mt * 16 + l15, q);
#pragma unroll
        for (int nt = 0; nt < 4; nt++) bfv[nt] = lds_frag(Bs, nbase + nt * 16 + l15, q);
#pragma unroll
        for (int mt = 0; mt < 4; mt++)
#pragma unroll
            for (int nt = 0; nt < 4; nt++)
                acc[mt][nt] = __builtin_amdgcn_mfma_f32_16x16x32_bf16(af[mt], bfv[nt], acc[mt][nt], 0, 0, 0);
    }

    __syncthreads();
#pragma unroll
    for (int mt = 0; mt < 4; mt++) {
        int co = co0 + mbase + mt * 16 + q * 4;
        f32x4 sc = *(const f32x4*)(s1 + co);
        f32x4 tc = *(const f32x4*)(t1 + co);
#pragma unroll
        for (int nt = 0; nt < 4; nt++) {
            int pxl = nbase + nt * 16 + l15;
            bf16x4 o;
#pragma unroll
            for (int r = 0; r < 4; r++) {
                float v = acc[mt][nt][r] * sc[r] + tc[r];
                o[r] = (bf16)(v > 0.f ? v : 0.f);
            }
            *(bf16x4*)(SH + pxl * 136 + mbase + mt * 16 + q * 4) = o;
        }
    }
    __syncthreads();
#pragma unroll
    for (int i = 0; i < 8; i++) {
        int v = t + 256 * i;
        int pxl = v >> 4, c16 = v & 15;
        *(uint4*)(h1 + (size_t)(p0 + pxl) * 1024 + co0 + c16 * 8) = *(const uint4*)(SH + pxl * 136 + c16 * 8);
    }
}

// ---------------- conv2: 1x1 1024->128 ----------------
__global__ __launch_bounds__(256) void conv2_gemm(const bf16* __restrict__ A2, const bf16* __restrict__ h1,
                                                  const float* __restrict__ s2, const float* __restrict__ t2,
                                                  bf16* __restrict__ hp) {
    __shared__ __align__(16) bf16 SH[17408];
    bf16* As = SH;
    bf16* Bs = SH + 4096;
    const int t = threadIdx.x;
    const int p0 = blockIdx.x * 128;
    const int wid = t >> 6, lane = t & 63;

    int aOff[2], bOff[2], ldsOff[2];
#pragma unroll
    for (int j = 0; j < 2; j++) {
        int p = wid * 128 + j * 64 + lane;
        int row = p >> 2;
        int oc = (p & 3) ^ ((p >> 3) & 3);
        aOff[j] = row * 1024 + oc * 8;
        bOff[j] = (p0 + row) * 1024 + oc * 8;
        ldsOff[j] = (wid * 128 + j * 64) * 8;
    }
    const int mbase = (wid & 1) * 64, nbase = (wid >> 1) * 64;
    const int l15 = lane & 15, q = lane >> 4;

    f32x4 acc[4][4];
#pragma unroll
    for (int i = 0; i < 4; i++)
#pragma unroll
        for (int j = 0; j < 4; j++) acc[i][j] = f32x4{0.f, 0.f, 0.f, 0.f};

    for (int ch = 0; ch < 32; ch++) {
        int k0 = ch * 32;
        __syncthreads();
#pragma unroll
        for (int j = 0; j < 2; j++) {
            g2l16(A2 + aOff[j] + k0, As + ldsOff[j]);
            g2l16(h1 + bOff[j] + k0, Bs + ldsOff[j]);
        }
        __syncthreads();
        bf16x8 af[4], bfv[4];
#pragma unroll
        for (int mt = 0; mt < 4; mt++) af[mt] = lds_frag(As, mbase + mt * 16 + l15, q);
#pragma unroll
        for (int nt = 0; nt < 4; nt++) bfv[nt] = lds_frag(Bs, nbase + nt * 16 + l15, q);
#pragma unroll
        for (int mt = 0; mt < 4; mt++)
#pragma unroll
            for (int nt = 0; nt < 4; nt++)
                acc[mt][nt] = __builtin_amdgcn_mfma_f32_16x16x32_bf16(af[mt], bfv[nt], acc[mt][nt], 0, 0, 0);
    }

    __syncthreads();
#pragma unroll
    for (int mt = 0; mt < 4; mt++) {
        int co = mbase + mt * 16 + q * 4;
        f32x4 sc = *(const f32x4*)(s2 + co);
        f32x4 tc = *(const f32x4*)(t2 + co);
#pragma unroll
        for (int nt = 0; nt < 4; nt++) {
            int pxl = nbase + nt * 16 + l15;
            bf16x4 o;
#pragma unroll
            for (int r = 0; r < 4; r++) {
                float v = acc[mt][nt][r] * sc[r] + tc[r];
                o[r] = (bf16)(v > 0.f ? v : 0.f);
            }
            *(bf16x4*)(SH + pxl * 136 + co) = o;
        }
    }
    __syncthreads();
#pragma unroll
    for (int i = 0; i < 8; i++) {
        int v = t + 256 * i;
        int pxl = v >> 4, c16 = v & 15;
        int p = p0 + pxl;
        int b = p / 3600, rr = p % 3600;
        int y = rr / 100, xx = rr % 100;
        *(uint4*)(hp + (size_t)((b * YS + y + 4) * XSZ + xx + 4) * 128 + c16 * 8) = *(const uint4*)(SH + pxl * 136 + c16 * 8);
    }
}

// ---------------- fused message passes ----------------
// One block per batch; 4 sequential phases (UD,DU,LR,RL). Waves split co
// (32 co/wave, 2 m-tiles). Each wave's A slice lives in REGISTERS, loaded
// once per phase (36x2 bf16x8 = 288 VGPRs; launch_bounds(256,1) -> 512
// budget, no spill). Per step only B comes from LDS.
__device__ __forceinline__ bf16x8 awfrag(const bf16* __restrict__ Aw, int ch, int mt, int l15, int q) {
    int t9 = ch >> 2, c0 = (ch & 3) << 5;
    return *(const bf16x8*)(Aw + (size_t)((t9 * 128 + mt * 16 + l15) << 7) + c0 + q * 8);
}

template <int AX, int RV>
__device__ void msg_phase(const bf16* __restrict__ Aw, bf16* __restrict__ hpb,
                          bf16* __restrict__ Rb, int t) {
    constexpr int STEPS = (AX == 2) ? NH : NW;
    constexpr int NLIM  = (AX == 2) ? NW : NH;
    constexpr int NT    = (AX == 2) ? 7 : 3;
    constexpr int LINE  = (AX == 2) ? XSZ : YS;
    const int wid = t >> 6, lane = t & 63, l15 = lane & 15, q = lane >> 4;

    // A slice -> registers, once per phase
    bf16x8 a[36][2];
#pragma unroll
    for (int ch = 0; ch < 36; ch++)
#pragma unroll
        for (int mt = 0; mt < 2; mt++)
            a[ch][mt] = awfrag(Aw, ch, wid * 2 + mt, l15, q);

    __threadfence();   // prior phase's global stores -> visible (L1 invalidate)

    // stage first (unchanged) line into LDS, incl. zero borders
    if (AX == 2) {
        int ys0 = RV ? 39 : 4;
        for (int v = t; v < LINE * 16; v += 256) {
            int xs = v >> 4, oct = v & 15;
            *(uint4*)(Rb + xs * 136 + oct * 8) = *(const uint4*)(hpb + ((size_t)ys0 * XSZ + xs) * 128 + oct * 8);
        }
    } else {
        int xs0 = RV ? 103 : 4;
        for (int v = t; v < LINE * 16; v += 256) {
            int ys = v >> 4, oct = v & 15;
            *(uint4*)(Rb + ys * 136 + oct * 8) = *(const uint4*)(hpb + ((size_t)ys * XSZ + xs0) * 128 + oct * 8);
        }
    }
    __syncthreads();

    for (int s = 1; s < STEPS; s++) {
        int pos = RV ? (STEPS - 1 - s) : s;

        f32x4 acc[2][NT];
#pragma unroll
        for (int mt = 0; mt < 2; mt++)
#pragma unroll
            for (int nt = 0; nt < NT; nt++) acc[mt][nt] = f32x4{0.f, 0.f, 0.f, 0.f};

#pragma unroll
        for (int ch = 0; ch < 36; ch++) {
            int t9 = ch >> 2, c0 = (ch & 3) << 5;
            bf16x8 bfv[NT];
#pragma unroll
            for (int nt = 0; nt < NT; nt++)
                bfv[nt] = *(const bf16x8*)(Rb + (nt * 16 + l15 + t9) * 136 + c0 + q * 8);
#pragma unroll
            for (int mt = 0; mt < 2; mt++)
#pragma unroll
                for (int nt = 0; nt < NT; nt++)
                    acc[mt][nt] = __builtin_amdgcn_mfma_f32_16x16x32_bf16(a[ch][mt], bfv[nt], acc[mt][nt], 0, 0, 0);
        }
        __syncthreads();   // all Rb reads done before overwrite

        // batched RMW: loads first (one latency exposure), then stores
        bf16x4 curv[2][NT];
#pragma unroll
        for (int mt = 0; mt < 2; mt++) {
            int co = wid * 32 + mt * 16 + q * 4;
#pragma unroll
            for (int nt = 0; nt < NT; nt++) {
                int n = nt * 16 + l15;
                if (n < NLIM) {
                    int g = (AX == 2) ? ((pos + 4) * XSZ + (n + 4)) * 128 + co
                                      : ((n + 4) * XSZ + (pos + 4)) * 128 + co;
                    curv[mt][nt] = *(const bf16x4*)(hpb + g);
                }
            }
        }
#pragma unroll
        for (int mt = 0; mt < 2; mt++) {
            int co = wid * 32 + mt * 16 + q * 4;
#pragma unroll
            for (int nt = 0; nt < NT; nt++) {
                int n = nt * 16 + l15;
                if (n < NLIM) {
                    int g = (AX == 2) ? ((pos + 4) * XSZ + (n + 4)) * 128 + co
                                      : ((n + 4) * XSZ + (pos + 4)) * 128 + co;
                    bf16x4 o;
#pragma unroll
                    for (int r = 0; r < 4; r++) {
                        float v = acc[mt][nt][r];
                        v = v > 0.f ? v : 0.f;
                        o[r] = (bf16)((float)curv[mt][nt][r] + v);
                    }
                    *(bf16x4*)(hpb + g) = o;
                    *(bf16x4*)(Rb + (n + 4) * 136 + co) = o;
                }
            }
        }
        __syncthreads();   // Rb writes done before next step's reads
    }
}

__global__ __launch_bounds__(256, 1) void msg_fused(const bf16* __restrict__ Aw, bf16* __restrict__ hp) {
    // 120 rows cover AX2 fragment-read overshoot (n<=111, +t9<=8); 65280 B < 64 KiB
    __shared__ __align__(16) bf16 Rb[120 * 136];
    const int b = blockIdx.x;
    const int t = threadIdx.x;
    bf16* hpb = hp + (size_t)b * YS * XSZ * 128;

    msg_phase<2, 0>(Aw + 0 * 147456, hpb, Rb, t);
    __syncthreads();
    msg_phase<2, 1>(Aw + 1 * 147456, hpb, Rb, t);
    __syncthreads();
    msg_phase<3, 0>(Aw + 2 * 147456, hpb, Rb, t);
    __syncthreads();
    msg_phase<3, 1>(Aw + 3 * 147456, hpb, Rb, t);
}

// ---------------- conv3 (1x1 128->5) + bias + softmax ----------------
__global__ __launch_bounds__(256) void conv3_softmax(const bf16* __restrict__ hp, const float* __restrict__ w2,
                                                     const float* __restrict__ b2, float* __restrict__ h5,
                                                     float* __restrict__ Pp) {
    int idx = blockIdx.x * 256 + threadIdx.x;
    if (idx >= PIX) return;
    int b = idx / 3600, rr = idx % 3600;
    int y = rr / 100, xx = rr % 100;
    const bf16* src = hp + ((size_t)(b * YS + y + 4) * XSZ + xx + 4) * 128;
    float a[5] = {b2[0], b2[1], b2[2], b2[3], b2[4]};
    for (int c8 = 0; c8 < 128; c8 += 8) {
        bf16x8 hv = *(const bf16x8*)(src + c8);
#pragma unroll
        for (int j = 0; j < 8; j++) {
            float hf = (float)hv[j];
            int c = c8 + j;
#pragma unroll
            for (int o = 0; o < 5; o++) a[o] += hf * w2[o * 128 + c];
        }
    }
    float mx = a[0];
#pragma unroll
    for (int o = 1; o < 5; o++) mx = a[o] > mx ? a[o] : mx;
    float e[5], sum = 0.f;
#pragma unroll
    for (int o = 0; o < 5; o++) { e[o] = expf(a[o] - mx); sum += e[o]; }
    float inv = 1.f / sum;
#pragma unroll
    for (int o = 0; o < 5; o++) {
        h5[(size_t)(b * 5 + o) * 3600 + rr] = a[o];
        Pp[(size_t)(b * 5 + o) * 3600 + rr] = e[o] * inv;
    }
}

__global__ __launch_bounds__(256) void pool_k(const float* __restrict__ Pp, float* __restrict__ F) {
    int idx = blockIdx.x * 256 + threadIdx.x;
    if (idx >= 36000) return;
    int xxp = idx % 50, r = idx / 50;
    int yyp = r % 18, bj = r / 18;
    int b = bj / 5, j = bj % 5;
    const float* Pb = Pp + (size_t)bj * 3600;
    float v = 0.25f * (Pb[(2 * yyp) * 100 + 2 * xxp] + Pb[(2 * yyp) * 100 + 2 * xxp + 1] +
                       Pb[(2 * yyp + 1) * 100 + 2 * xxp] + Pb[(2 * yyp + 1) * 100 + 2 * xxp + 1]);
    F[(size_t)b * 4500 + j * 900 + yyp * 50 + xxp] = v;
}

__global__ __launch_bounds__(64) void fc1_k(const float* __restrict__ F, const float* __restrict__ w,
                                            const float* __restrict__ bias, float* __restrict__ G) {
    int co = blockIdx.x;
    int lane = threadIdx.x;
    const float* wr = w + (size_t)co * 4500;
    float a[8] = {0.f, 0.f, 0.f, 0.f, 0.f, 0.f, 0.f, 0.f};
    for (int k = lane; k < 4500; k += 64) {
        float wv = wr[k];
#pragma unroll
        for (int b = 0; b < 8; b++) a[b] += wv * F[b * 4500 + k];
    }
#pragma unroll
    for (int b = 0; b < 8; b++) {
        float r = a[b];
        for (int off = 32; off; off >>= 1) r += __shfl_down(r, off);
        if (lane == 0) {
            float v = r + bias[co];
            G[b * 128 + co] = v > 0.f ? v : 0.f;
        }
    }
}

__global__ __launch_bounds__(64) void fc2_k(const float* __restrict__ G, const float* __restrict__ w,
                                            const float* __restrict__ bias, float* __restrict__ out) {
    int t = threadIdx.x;
    if (t >= 32) return;
    int b = t >> 2, j = t & 3;
    float a = bias[j];
    for (int c = 0; c < 128; c++) a += G[b * 128 + c] * w[j * 128 + c];
    out[9216000 + b * 4 + j] = 1.f / (1.f + expf(-a));
}

__global__ __launch_bounds__(256) void upsample_k(const float* __restrict__ h5, float* __restrict__ out) {
    int idx = blockIdx.x * 256 + threadIdx.x;
    if (idx >= 2304000) return;
    int xq = idx % 200, r = idx / 200;
    int yo = r % 288, bj = r / 288;
    const float* src = h5 + (size_t)bj * 3600;
    float py = yo * (35.0f / 287.0f);
    int i0 = (int)py; if (i0 > 34) i0 = 34;
    float fh = py - (float)i0;
    const float* r0 = src + i0 * 100;
    const float* r1 = r0 + 100;
    float4 o;
    float res[4];
#pragma unroll
    for (int e = 0; e < 4; e++) {
        int xo = xq * 4 + e;
        float px = xo * (99.0f / 799.0f);
        int j0 = (int)px; if (j0 > 98) j0 = 98;
        float fw = px - (float)j0;
        float aa = r0[j0] * (1.f - fh) + r1[j0] * fh;
        float bb = r0[j0 + 1] * (1.f - fh) + r1[j0 + 1] * fh;
        res[e] = aa * (1.f - fw) + bb * fw;
    }
    o.x = res[0]; o.y = res[1]; o.z = res[2]; o.w = res[3];
    *(float4*)(out + (size_t)idx * 4) = o;
}

// ---------------- launcher ----------------
extern "C" void kernel_launch(void* const* d_in, const int* in_sizes, int n_in,
                              void* d_out, int out_size, void* d_ws, size_t ws_size,
                              hipStream_t stream) {
    (void)in_sizes; (void)n_in; (void)out_size; (void)ws_size;
    const float* x    = (const float*)d_in[0];
    const float* w1a  = (const float*)d_in[1];
    const float* bn1g = (const float*)d_in[2];
    const float* bn1b = (const float*)d_in[3];
    const float* bn1m = (const float*)d_in[4];
    const float* bn1v = (const float*)d_in[5];
    const float* w1b  = (const float*)d_in[6];
    const float* bn2g = (const float*)d_in[7];
    const float* bn2b = (const float*)d_in[8];
    const float* bn2m = (const float*)d_in[9];
    const float* bn2v = (const float*)d_in[10];
    const float* wud  = (const float*)d_in[11];
    const float* wdu  = (const float*)d_in[12];
    const float* wlr  = (const float*)d_in[13];
    const float* wrl  = (const float*)d_in[14];
    const float* w2   = (const float*)d_in[15];
    const float* b2   = (const float*)d_in[16];
    const float* fc1w = (const float*)d_in[17];
    const float* fc1b = (const float*)d_in[18];
    const float* fc2w = (const float*)d_in[19];
    const float* fc2b = (const float*)d_in[20];
    float* out = (float*)d_out;
    char* ws = (char*)d_ws;
    bf16* xp = (bf16*)(ws + OFF_XP);
    bf16* hp = (bf16*)(ws + OFF_HP);
    bf16* A1 = (bf16*)(ws + OFF_A1);
    bf16* A2 = (bf16*)(ws + OFF_A2);
    bf16* Aw = (bf16*)(ws + OFF_AW);
    bf16* h1 = (bf16*)(ws + OFF_H1);
    float* s1 = (float*)(ws + OFF_S1);
    float* t1 = (float*)(ws + OFF_T1);
    float* s2 = (float*)(ws + OFF_S2);
    float* t2 = (float*)(ws + OFF_T2);
    float* h5 = (float*)(ws + OFF_H5);
    float* Pp = (float*)(ws + OFF_P);
    float* Ff = (float*)(ws + OFF_F);
    float* Gg = (float*)(ws + OFF_G);

    int nzero = (int)((SZ_XP + SZ_HP) / 16);
    zero_k<<<(nzero + 255) / 256, 256, 0, stream>>>((uint4*)ws, nzero);
    prep_x<<<18432, 256, 0, stream>>>(x, xp);
    prep_w1a<<<1024, 256, 0, stream>>>(w1a, A1);
    prep_w1b<<<512, 256, 0, stream>>>(w1b, A2);
    prep_msg<<<2304, 256, 0, stream>>>(wud, wdu, wlr, wrl, Aw);
    prep_bn<<<5, 256, 0, stream>>>(bn1g, bn1b, bn1m, bn1v, bn2g, bn2b, bn2m, bn2v, s1, t1, s2, t2);

    conv1_gemm<<<dim3(225, 8), 256, 0, stream>>>(A1, xp, s1, t1, h1);
    conv2_gemm<<<225, 256, 0, stream>>>(A2, h1, s2, t2, hp);

    msg_fused<<<NB, 256, 0, stream>>>(Aw, hp);

    conv3_softmax<<<113, 256, 0, stream>>>(hp, w2, b2, h5, Pp);
    pool_k<<<141, 256, 0, stream>>>(Pp, Ff);
    fc1_k<<<128, 64, 0, stream>>>(Ff, fc1w, fc1b, Gg);
    fc2_k<<<1, 64, 0, stream>>>(Gg, fc2w, fc2b, out);
    upsample_k<<<9000, 256, 0, stream>>>(h5, out);
}

// Round 6
// 2120.613 us; speedup vs baseline: 3.4641x; 1.1347x over previous
//
#include <hip/hip_runtime.h>
#include <hip/hip_bf16.h>
#include <stdint.h>

typedef __bf16 bf16;
typedef bf16 bf16x8 __attribute__((ext_vector_type(8)));
typedef bf16 bf16x4 __attribute__((ext_vector_type(4)));
typedef float f32x4 __attribute__((ext_vector_type(4)));

#define NB 8
#define NH 36
#define NW 100
#define YS 44
#define XSZ 108
#define PIX 28800

#define AS1 __attribute__((address_space(1)))
#define AS3 __attribute__((address_space(3)))

// async 16B global->LDS DMA. Dest = wave-uniform base + lane*16.
__device__ __forceinline__ void g2l16(const bf16* g, bf16* l) {
    __builtin_amdgcn_global_load_lds((const AS1 void*)g, (AS3 void*)l, 16, 0, 0);
}

// ---------------- workspace layout ----------------
static constexpr size_t OFF_XP = 0;
static constexpr size_t SZ_XP  = (size_t)NB*YS*XSZ*512*2;
static constexpr size_t OFF_HP = OFF_XP + SZ_XP;
static constexpr size_t SZ_HP  = (size_t)NB*YS*XSZ*128*2;
static constexpr size_t OFF_A1 = OFF_HP + SZ_HP;
static constexpr size_t SZ_A1  = (size_t)1024*4608*2;
static constexpr size_t OFF_A2 = OFF_A1 + SZ_A1;
static constexpr size_t SZ_A2  = (size_t)128*1024*2;
static constexpr size_t OFF_AW = OFF_A2 + SZ_A2;
static constexpr size_t SZ_AW  = (size_t)4*9*128*128*2;
static constexpr size_t OFF_H1 = OFF_AW + SZ_AW;
static constexpr size_t SZ_H1  = (size_t)PIX*1024*2;
static constexpr size_t OFF_S1 = OFF_H1 + SZ_H1;
static constexpr size_t OFF_T1 = OFF_S1 + 4096;
static constexpr size_t OFF_S2 = OFF_T1 + 4096;
static constexpr size_t OFF_T2 = OFF_S2 + 512;
static constexpr size_t OFF_H5 = OFF_T2 + 512;
static constexpr size_t SZ_H5  = (size_t)NB*5*3600*4;
static constexpr size_t OFF_P  = OFF_H5 + SZ_H5;
static constexpr size_t OFF_F  = OFF_P + SZ_H5;
static constexpr size_t OFF_G  = OFF_F + 144128;
static constexpr size_t OFF_BAR = OFF_G + 4096;      // 8 x u32 barrier counters

// ---------------- prep kernels ----------------
__global__ __launch_bounds__(256) void zero_k(uint4* __restrict__ p, int n) {
    int i = blockIdx.x * 256 + threadIdx.x;
    if (i < n) p[i] = uint4{0u, 0u, 0u, 0u};
}

__global__ __launch_bounds__(256) void prep_x(const float* __restrict__ x, bf16* __restrict__ xp) {
    int bid = blockIdx.x;
    int xc = bid & 3;  int r = bid >> 2;
    int cc = r & 15;   r >>= 4;
    int yo = r % 36;   int b = r / 36;
    int ci0 = cc * 32, xo0 = xc * 32;
    int wdt = 100 - xo0; if (wdt > 32) wdt = 32;
    __shared__ bf16 T[32 * 33];
    int t = threadIdx.x;
    int cl = t >> 5, xl = t & 31;
    if (xl < wdt) {
#pragma unroll
        for (int i = 0; i < 4; i++) {
            int ci = ci0 + cl + 8 * i;
            T[(cl + 8 * i) * 33 + xl] = (bf16)x[((size_t)(b * 512 + ci) * 36 + yo) * 100 + xo0 + xl];
        }
    }
    __syncthreads();
    if (t < 128) {
        int xo2 = t >> 2, oct = t & 3;
        if (xo2 < wdt) {
            bf16x8 vv;
#pragma unroll
            for (int j = 0; j < 8; j++) vv[j] = T[(oct * 8 + j) * 33 + xo2];
            *(bf16x8*)(xp + ((size_t)((b * YS + yo + 4) * XSZ) + xo0 + xo2 + 4) * 512 + ci0 + oct * 8) = vv;
        }
    }
}

__global__ __launch_bounds__(256) void prep_w1a(const float* __restrict__ w, bf16* __restrict__ A) {
    int co = blockIdx.x;
    __shared__ bf16 Wl[4608];
    const float* src = w + (size_t)co * 4608;
    for (int v = threadIdx.x; v < 4608; v += 256) Wl[v] = (bf16)src[v];
    __syncthreads();
    bf16* dst = A + (size_t)co * 4608;
    for (int v = threadIdx.x; v < 4608; v += 256) {
        int rr = v >> 9, ci = v & 511;
        dst[v] = Wl[ci * 9 + rr];
    }
}

__global__ __launch_bounds__(256) void prep_w1b(const float* __restrict__ w, bf16* __restrict__ A) {
    int i = blockIdx.x * 256 + threadIdx.x;
    if (i < 131072) A[i] = (bf16)w[i];
}

__global__ __launch_bounds__(256) void prep_msg(const float* __restrict__ w0, const float* __restrict__ w1,
                                                const float* __restrict__ w2m, const float* __restrict__ w3,
                                                bf16* __restrict__ Aw) {
    int idx = blockIdx.x * 256 + threadIdx.x;
    if (idx >= 4 * 147456) return;
    int w = idx / 147456, r = idx % 147456;
    int t9 = r / 16384, r2 = r % 16384;
    int co = r2 >> 7, ci = r2 & 127;
    const float* s = (w == 0) ? w0 : (w == 1) ? w1 : (w == 2) ? w2m : w3;
    Aw[idx] = (bf16)s[(co * 128 + ci) * 9 + t9];
}

__global__ __launch_bounds__(256) void prep_bn(const float* g1, const float* b1, const float* m1, const float* v1,
                                               const float* g2, const float* b2i, const float* m2, const float* v2,
                                               float* s1, float* t1, float* s2, float* t2,
                                               unsigned* bar) {
    int i = blockIdx.x * 256 + threadIdx.x;
    if (i < 1024) {
        float s = g1[i] / sqrtf(v1[i] + 1e-5f);
        s1[i] = s; t1[i] = b1[i] - m1[i] * s;
    } else if (i < 1152) {
        int c = i - 1024;
        float s = g2[c] / sqrtf(v2[c] + 1e-5f);
        s2[c] = s; t2[c] = b2i[c] - m2[c] * s;
    } else if (i < 1160) {
        bar[i - 1152] = 0u;                 // reset msg barrier counters each launch
    }
}

// ---------------- conv1: implicit-im2col GEMM, global_load_lds + swizzled LDS ----------------
__device__ __forceinline__ void c1_koff(int ch, int& k0, int& xoff) {
    int ky = ch / 48, rem = ch - ky * 48;
    int kx = rem >> 4, c0 = (rem & 15) << 5;
    k0 = (ky * 3 + kx) * 512 + c0;
    xoff = (ky * XSZ + kx) * 2048 + c0;
}

__device__ __forceinline__ bf16x8 lds_frag(const bf16* S, int row, int q) {
    return *(const bf16x8*)(S + row * 32 + (((q ^ (row >> 1)) & 3) * 8));
}

__global__ __launch_bounds__(256) void conv1_gemm(const bf16* __restrict__ A, const bf16* __restrict__ xp,
                                                  const float* __restrict__ s1, const float* __restrict__ t1,
                                                  bf16* __restrict__ h1) {
    __shared__ __align__(16) bf16 SH[17408];
    bf16* As = SH;
    bf16* Bs = SH + 4096;
    const int t = threadIdx.x;
    const int pt = blockIdx.x, ct = blockIdx.y;
    const int co0 = ct * 128, p0 = pt * 128;
    const int wid = t >> 6, lane = t & 63;

    int aOff[2], bOff[2], ldsOff[2];
#pragma unroll
    for (int j = 0; j < 2; j++) {
        int p = wid * 128 + j * 64 + lane;
        int row = p >> 2;
        int oc = (p & 3) ^ ((p >> 3) & 3);
        aOff[j] = (co0 + row) * 4608 + oc * 8;
        int px = p0 + row;
        int b = px / 3600, rr = px % 3600;
        int y = rr / 100, xx = rr % 100;
        bOff[j] = ((b * YS + y) * XSZ + xx) * 512 + oc * 8;
        ldsOff[j] = (wid * 128 + j * 64) * 8;
    }

    const int mbase = (wid & 1) * 64, nbase = (wid >> 1) * 64;
    const int l15 = lane & 15, q = lane >> 4;

    f32x4 acc[4][4];
#pragma unroll
    for (int i = 0; i < 4; i++)
#pragma unroll
        for (int j = 0; j < 4; j++) acc[i][j] = f32x4{0.f, 0.f, 0.f, 0.f};

    for (int ch = 0; ch < 144; ch++) {
        int k0, xoff;
        c1_koff(ch, k0, xoff);
        __syncthreads();
#pragma unroll
        for (int j = 0; j < 2; j++) {
            g2l16(A + aOff[j] + k0, As + ldsOff[j]);
            g2l16(xp + bOff[j] + xoff, Bs + ldsOff[j]);
        }
        __syncthreads();
        bf16x8 af[4], bfv[4];
#pragma unroll
        for (int mt = 0; mt < 4; mt++) af[mt] = lds_frag(As, mbase + mt * 16 + l15, q);
#pragma unroll
        for (int nt = 0; nt < 4; nt++) bfv[nt] = lds_frag(Bs, nbase + nt * 16 + l15, q);
#pragma unroll
        for (int mt = 0; mt < 4; mt++)
#pragma unroll
            for (int nt = 0; nt < 4; nt++)
                acc[mt][nt] = __builtin_amdgcn_mfma_f32_16x16x32_bf16(af[mt], bfv[nt], acc[mt][nt], 0, 0, 0);
    }

    __syncthreads();
#pragma unroll
    for (int mt = 0; mt < 4; mt++) {
        int co = co0 + mbase + mt * 16 + q * 4;
        f32x4 sc = *(const f32x4*)(s1 + co);
        f32x4 tc = *(const f32x4*)(t1 + co);
#pragma unroll
        for (int nt = 0; nt < 4; nt++) {
            int pxl = nbase + nt * 16 + l15;
            bf16x4 o;
#pragma unroll
            for (int r = 0; r < 4; r++) {
                float v = acc[mt][nt][r] * sc[r] + tc[r];
                o[r] = (bf16)(v > 0.f ? v : 0.f);
            }
            *(bf16x4*)(SH + pxl * 136 + mbase + mt * 16 + q * 4) = o;
        }
    }
    __syncthreads();
#pragma unroll
    for (int i = 0; i < 8; i++) {
        int v = t + 256 * i;
        int pxl = v >> 4, c16 = v & 15;
        *(uint4*)(h1 + (size_t)(p0 + pxl) * 1024 + co0 + c16 * 8) = *(const uint4*)(SH + pxl * 136 + c16 * 8);
    }
}

// ---------------- conv2: 1x1 1024->128 ----------------
__global__ __launch_bounds__(256) void conv2_gemm(const bf16* __restrict__ A2, const bf16* __restrict__ h1,
                                                  const float* __restrict__ s2, const float* __restrict__ t2,
                                                  bf16* __restrict__ hp) {
    __shared__ __align__(16) bf16 SH[17408];
    bf16* As = SH;
    bf16* Bs = SH + 4096;
    const int t = threadIdx.x;
    const int p0 = blockIdx.x * 128;
    const int wid = t >> 6, lane = t & 63;

    int aOff[2], bOff[2], ldsOff[2];
#pragma unroll
    for (int j = 0; j < 2; j++) {
        int p = wid * 128 + j * 64 + lane;
        int row = p >> 2;
        int oc = (p & 3) ^ ((p >> 3) & 3);
        aOff[j] = row * 1024 + oc * 8;
        bOff[j] = (p0 + row) * 1024 + oc * 8;
        ldsOff[j] = (wid * 128 + j * 64) * 8;
    }
    const int mbase = (wid & 1) * 64, nbase = (wid >> 1) * 64;
    const int l15 = lane & 15, q = lane >> 4;

    f32x4 acc[4][4];
#pragma unroll
    for (int i = 0; i < 4; i++)
#pragma unroll
        for (int j = 0; j < 4; j++) acc[i][j] = f32x4{0.f, 0.f, 0.f, 0.f};

    for (int ch = 0; ch < 32; ch++) {
        int k0 = ch * 32;
        __syncthreads();
#pragma unroll
        for (int j = 0; j < 2; j++) {
            g2l16(A2 + aOff[j] + k0, As + ldsOff[j]);
            g2l16(h1 + bOff[j] + k0, Bs + ldsOff[j]);
        }
        __syncthreads();
        bf16x8 af[4], bfv[4];
#pragma unroll
        for (int mt = 0; mt < 4; mt++) af[mt] = lds_frag(As, mbase + mt * 16 + l15, q);
#pragma unroll
        for (int nt = 0; nt < 4; nt++) bfv[nt] = lds_frag(Bs, nbase + nt * 16 + l15, q);
#pragma unroll
        for (int mt = 0; mt < 4; mt++)
#pragma unroll
            for (int nt = 0; nt < 4; nt++)
                acc[mt][nt] = __builtin_amdgcn_mfma_f32_16x16x32_bf16(af[mt], bfv[nt], acc[mt][nt], 0, 0, 0);
    }

    __syncthreads();
#pragma unroll
    for (int mt = 0; mt < 4; mt++) {
        int co = mbase + mt * 16 + q * 4;
        f32x4 sc = *(const f32x4*)(s2 + co);
        f32x4 tc = *(const f32x4*)(t2 + co);
#pragma unroll
        for (int nt = 0; nt < 4; nt++) {
            int pxl = nbase + nt * 16 + l15;
            bf16x4 o;
#pragma unroll
            for (int r = 0; r < 4; r++) {
                float v = acc[mt][nt][r] * sc[r] + tc[r];
                o[r] = (bf16)(v > 0.f ? v : 0.f);
            }
            *(bf16x4*)(SH + pxl * 136 + co) = o;
        }
    }
    __syncthreads();
#pragma unroll
    for (int i = 0; i < 8; i++) {
        int v = t + 256 * i;
        int pxl = v >> 4, c16 = v & 15;
        int p = p0 + pxl;
        int b = p / 3600, rr = p % 3600;
        int y = rr / 100, xx = rr % 100;
        *(uint4*)(hp + (size_t)((b * YS + y + 4) * XSZ + xx + 4) * 128 + c16 * 8) = *(const uint4*)(SH + pxl * 136 + c16 * 8);
    }
}

// ---------------- fused message passes, 8 blocks per batch ----------------
// 64 blocks = 8 batches x 8 co-slices(16). Per wave: A slice = 36 frags =
// 144 VGPRs (fits the 256 arch-VGPR cap). Waves split n (no B redundancy).
// Per step: re-stage prev line from global (L2-hot), MFMA, RMW store, then
// release/acquire barrier among the batch's 8 blocks. batch = blockIdx&7
// keeps each batch-group on one XCD (b%8 heuristic, perf-only).
__device__ __forceinline__ bf16x8 awfrag2(const bf16* __restrict__ Aw, int ch, int cs, int l15, int q) {
    int t9 = ch >> 2, c0 = (ch & 3) << 5;
    return *(const bf16x8*)(Aw + (size_t)((t9 * 128 + cs * 16 + l15) << 7) + c0 + q * 8);
}

__device__ __forceinline__ void gbar(unsigned* ctr, int target) {
    __syncthreads();                     // all waves' stores issued
    if (threadIdx.x == 0) {
        __hip_atomic_fetch_add(ctr, 1u, __ATOMIC_RELEASE, __HIP_MEMORY_SCOPE_AGENT);
        while ((int)__hip_atomic_load(ctr, __ATOMIC_ACQUIRE, __HIP_MEMORY_SCOPE_AGENT) < target)
            __builtin_amdgcn_s_sleep(2);
    }
    __syncthreads();
}

template <int AX, int RV>
__device__ void msg_phase2(const bf16* __restrict__ Aw, bf16* __restrict__ hpb,
                           bf16* __restrict__ Rb, unsigned* ctr, int cs, int& ep) {
    constexpr int STEPS = (AX == 2) ? NH : NW;
    constexpr int NLIM  = (AX == 2) ? NW : NH;
    constexpr int NTW   = (AX == 2) ? 2 : 1;
    const int t = threadIdx.x, wid = t >> 6, lane = t & 63, l15 = lane & 15, q = lane >> 4;

    // this block's 16-co weight slice -> registers (same in all 4 waves)
    bf16x8 a[36];
#pragma unroll
    for (int ch = 0; ch < 36; ch++) a[ch] = awfrag2(Aw, ch, cs, l15, q);

    const int nb0 = (AX == 2) ? wid * 32 : wid * 16;
    bool act[NTW];
#pragma unroll
    for (int i = 0; i < NTW; i++) act[i] = (nb0 + i * 16) < NLIM;
    const int co = cs * 16 + q * 4;

    for (int s = 1; s < STEPS; s++) {
        int pos = RV ? (STEPS - 1 - s) : s;
        int prv = RV ? pos + 1 : pos - 1;

        // stage prev line (all 128 ci) into Rb from global
        if (AX == 2) {
            const bf16* src = hpb + (size_t)(prv + 4) * XSZ * 128;
            for (int v = t; v < 108 * 16; v += 256) {
                int px = v >> 4, c = (v & 15) * 8;
                *(uint4*)(Rb + px * 136 + c) = *(const uint4*)(src + px * 128 + c);
            }
        } else {
            const bf16* src = hpb + (size_t)(prv + 4) * 128;
            for (int v = t; v < 44 * 16; v += 256) {
                int ys = v >> 4, c = (v & 15) * 8;
                *(uint4*)(Rb + ys * 136 + c) = *(const uint4*)(src + (size_t)ys * XSZ * 128 + c);
            }
        }
        __syncthreads();

        f32x4 acc[NTW];
#pragma unroll
        for (int i = 0; i < NTW; i++) acc[i] = f32x4{0.f, 0.f, 0.f, 0.f};
#pragma unroll
        for (int ch = 0; ch < 36; ch++) {
            int t9 = ch >> 2, c0 = (ch & 3) << 5;
#pragma unroll
            for (int i = 0; i < NTW; i++) {
                if (act[i]) {
                    bf16x8 bfv = *(const bf16x8*)(Rb + (nb0 + i * 16 + l15 + t9) * 136 + c0 + q * 8);
                    acc[i] = __builtin_amdgcn_mfma_f32_16x16x32_bf16(a[ch], bfv, acc[i], 0, 0, 0);
                }
            }
        }

        // RMW this block's 16-co slice of row/col pos
#pragma unroll
        for (int i = 0; i < NTW; i++) {
            if (act[i]) {
                int n = nb0 + i * 16 + l15;
                if (n < NLIM) {
                    size_t g = (AX == 2) ? ((size_t)(pos + 4) * XSZ + (n + 4)) * 128 + co
                                         : ((size_t)(n + 4) * XSZ + (pos + 4)) * 128 + co;
                    bf16x4 cur = *(const bf16x4*)(hpb + g);
                    bf16x4 o;
#pragma unroll
                    for (int r = 0; r < 4; r++) {
                        float v = acc[i][r];
                        v = v > 0.f ? v : 0.f;
                        o[r] = (bf16)((float)cur[r] + v);
                    }
                    *(bf16x4*)(hpb + g) = o;
                }
            }
        }
        ep++;
        gbar(ctr, 8 * ep);               // line complete + visible to group
    }
}

__global__ __launch_bounds__(256, 1) void msg_fused(const bf16* __restrict__ Aw, bf16* __restrict__ hp,
                                                    unsigned* __restrict__ bar) {
    __shared__ __align__(16) bf16 Rb[120 * 136];   // 32.6 KB (AX2 reads up to row 119)
    const int batch = blockIdx.x & 7;              // same XCD per batch-group (b%8)
    const int cs = blockIdx.x >> 3;                // co-slice 0..7
    bf16* hpb = hp + (size_t)batch * YS * XSZ * 128;
    unsigned* ctr = bar + batch;
    int ep = 0;
    msg_phase2<2, 0>(Aw + 0 * 147456, hpb, Rb, ctr, cs, ep);
    msg_phase2<2, 1>(Aw + 1 * 147456, hpb, Rb, ctr, cs, ep);
    msg_phase2<3, 0>(Aw + 2 * 147456, hpb, Rb, ctr, cs, ep);
    msg_phase2<3, 1>(Aw + 3 * 147456, hpb, Rb, ctr, cs, ep);
}

// ---------------- conv3 (1x1 128->5) + bias + softmax ----------------
__global__ __launch_bounds__(256) void conv3_softmax(const bf16* __restrict__ hp, const float* __restrict__ w2,
                                                     const float* __restrict__ b2, float* __restrict__ h5,
                                                     float* __restrict__ Pp) {
    int idx = blockIdx.x * 256 + threadIdx.x;
    if (idx >= PIX) return;
    int b = idx / 3600, rr = idx % 3600;
    int y = rr / 100, xx = rr % 100;
    const bf16* src = hp + ((size_t)(b * YS + y + 4) * XSZ + xx + 4) * 128;
    float a[5] = {b2[0], b2[1], b2[2], b2[3], b2[4]};
    for (int c8 = 0; c8 < 128; c8 += 8) {
        bf16x8 hv = *(const bf16x8*)(src + c8);
#pragma unroll
        for (int j = 0; j < 8; j++) {
            float hf = (float)hv[j];
            int c = c8 + j;
#pragma unroll
            for (int o = 0; o < 5; o++) a[o] += hf * w2[o * 128 + c];
        }
    }
    float mx = a[0];
#pragma unroll
    for (int o = 1; o < 5; o++) mx = a[o] > mx ? a[o] : mx;
    float e[5], sum = 0.f;
#pragma unroll
    for (int o = 0; o < 5; o++) { e[o] = expf(a[o] - mx); sum += e[o]; }
    float inv = 1.f / sum;
#pragma unroll
    for (int o = 0; o < 5; o++) {
        h5[(size_t)(b * 5 + o) * 3600 + rr] = a[o];
        Pp[(size_t)(b * 5 + o) * 3600 + rr] = e[o] * inv;
    }
}

__global__ __launch_bounds__(256) void pool_k(const float* __restrict__ Pp, float* __restrict__ F) {
    int idx = blockIdx.x * 256 + threadIdx.x;
    if (idx >= 36000) return;
    int xxp = idx % 50, r = idx / 50;
    int yyp = r % 18, bj = r / 18;
    int b = bj / 5, j = bj % 5;
    const float* Pb = Pp + (size_t)bj * 3600;
    float v = 0.25f * (Pb[(2 * yyp) * 100 + 2 * xxp] + Pb[(2 * yyp) * 100 + 2 * xxp + 1] +
                       Pb[(2 * yyp + 1) * 100 + 2 * xxp] + Pb[(2 * yyp + 1) * 100 + 2 * xxp + 1]);
    F[(size_t)b * 4500 + j * 900 + yyp * 50 + xxp] = v;
}

__global__ __launch_bounds__(64) void fc1_k(const float* __restrict__ F, const float* __restrict__ w,
                                            const float* __restrict__ bias, float* __restrict__ G) {
    int co = blockIdx.x;
    int lane = threadIdx.x;
    const float* wr = w + (size_t)co * 4500;
    float a[8] = {0.f, 0.f, 0.f, 0.f, 0.f, 0.f, 0.f, 0.f};
    for (int k = lane; k < 4500; k += 64) {
        float wv = wr[k];
#pragma unroll
        for (int b = 0; b < 8; b++) a[b] += wv * F[b * 4500 + k];
    }
#pragma unroll
    for (int b = 0; b < 8; b++) {
        float r = a[b];
        for (int off = 32; off; off >>= 1) r += __shfl_down(r, off);
        if (lane == 0) {
            float v = r + bias[co];
            G[b * 128 + co] = v > 0.f ? v : 0.f;
        }
    }
}

__global__ __launch_bounds__(64) void fc2_k(const float* __restrict__ G, const float* __restrict__ w,
                                            const float* __restrict__ bias, float* __restrict__ out) {
    int t = threadIdx.x;
    if (t >= 32) return;
    int b = t >> 2, j = t & 3;
    float a = bias[j];
    for (int c = 0; c < 128; c++) a += G[b * 128 + c] * w[j * 128 + c];
    out[9216000 + b * 4 + j] = 1.f / (1.f + expf(-a));
}

__global__ __launch_bounds__(256) void upsample_k(const float* __restrict__ h5, float* __restrict__ out) {
    int idx = blockIdx.x * 256 + threadIdx.x;
    if (idx >= 2304000) return;
    int xq = idx % 200, r = idx / 200;
    int yo = r % 288, bj = r / 288;
    const float* src = h5 + (size_t)bj * 3600;
    float py = yo * (35.0f / 287.0f);
    int i0 = (int)py; if (i0 > 34) i0 = 34;
    float fh = py - (float)i0;
    const float* r0 = src + i0 * 100;
    const float* r1 = r0 + 100;
    float4 o;
    float res[4];
#pragma unroll
    for (int e = 0; e < 4; e++) {
        int xo = xq * 4 + e;
        float px = xo * (99.0f / 799.0f);
        int j0 = (int)px; if (j0 > 98) j0 = 98;
        float fw = px - (float)j0;
        float aa = r0[j0] * (1.f - fh) + r1[j0] * fh;
        float bb = r0[j0 + 1] * (1.f - fh) + r1[j0 + 1] * fh;
        res[e] = aa * (1.f - fw) + bb * fw;
    }
    o.x = res[0]; o.y = res[1]; o.z = res[2]; o.w = res[3];
    *(float4*)(out + (size_t)idx * 4) = o;
}

// ---------------- launcher ----------------
extern "C" void kernel_launch(void* const* d_in, const int* in_sizes, int n_in,
                              void* d_out, int out_size, void* d_ws, size_t ws_size,
                              hipStream_t stream) {
    (void)in_sizes; (void)n_in; (void)out_size; (void)ws_size;
    const float* x    = (const float*)d_in[0];
    const float* w1a  = (const float*)d_in[1];
    const float* bn1g = (const float*)d_in[2];
    const float* bn1b = (const float*)d_in[3];
    const float* bn1m = (const float*)d_in[4];
    const float* bn1v = (const float*)d_in[5];
    const float* w1b  = (const float*)d_in[6];
    const float* bn2g = (const float*)d_in[7];
    const float* bn2b = (const float*)d_in[8];
    const float* bn2m = (const float*)d_in[9];
    const float* bn2v = (const float*)d_in[10];
    const float* wud  = (const float*)d_in[11];
    const float* wdu  = (const float*)d_in[12];
    const float* wlr  = (const float*)d_in[13];
    const float* wrl  = (const float*)d_in[14];
    const float* w2   = (const float*)d_in[15];
    const float* b2   = (const float*)d_in[16];
    const float* fc1w = (const float*)d_in[17];
    const float* fc1b = (const float*)d_in[18];
    const float* fc2w = (const float*)d_in[19];
    const float* fc2b = (const float*)d_in[20];
    float* out = (float*)d_out;
    char* ws = (char*)d_ws;
    bf16* xp = (bf16*)(ws + OFF_XP);
    bf16* hp = (bf16*)(ws + OFF_HP);
    bf16* A1 = (bf16*)(ws + OFF_A1);
    bf16* A2 = (bf16*)(ws + OFF_A2);
    bf16* Aw = (bf16*)(ws + OFF_AW);
    bf16* h1 = (bf16*)(ws + OFF_H1);
    float* s1 = (float*)(ws + OFF_S1);
    float* t1 = (float*)(ws + OFF_T1);
    float* s2 = (float*)(ws + OFF_S2);
    float* t2 = (float*)(ws + OFF_T2);
    float* h5 = (float*)(ws + OFF_H5);
    float* Pp = (float*)(ws + OFF_P);
    float* Ff = (float*)(ws + OFF_F);
    float* Gg = (float*)(ws + OFF_G);
    unsigned* bar = (unsigned*)(ws + OFF_BAR);

    int nzero = (int)((SZ_XP + SZ_HP) / 16);
    zero_k<<<(nzero + 255) / 256, 256, 0, stream>>>((uint4*)ws, nzero);
    prep_x<<<18432, 256, 0, stream>>>(x, xp);
    prep_w1a<<<1024, 256, 0, stream>>>(w1a, A1);
    prep_w1b<<<512, 256, 0, stream>>>(w1b, A2);
    prep_msg<<<2304, 256, 0, stream>>>(wud, wdu, wlr, wrl, Aw);
    prep_bn<<<5, 256, 0, stream>>>(bn1g, bn1b, bn1m, bn1v, bn2g, bn2b, bn2m, bn2v, s1, t1, s2, t2, bar);

    conv1_gemm<<<dim3(225, 8), 256, 0, stream>>>(A1, xp, s1, t1, h1);
    conv2_gemm<<<225, 256, 0, stream>>>(A2, h1, s2, t2, hp);

    msg_fused<<<64, 256, 0, stream>>>(Aw, hp, bar);

    conv3_softmax<<<113, 256, 0, stream>>>(hp, w2, b2, h5, Pp);
    pool_k<<<141, 256, 0, stream>>>(Pp, Ff);
    fc1_k<<<128, 64, 0, stream>>>(Ff, fc1w, fc1b, Gg);
    fc2_k<<<1, 64, 0, stream>>>(Gg, fc2w, fc2b, out);
    upsample_k<<<9000, 256, 0, stream>>>(h5, out);
}